// Round 2
// baseline (1352.732 us; speedup 1.0000x reference)
//
#include <hip/hip_runtime.h>

#define N_NODES 50000
#define N_EDGES 1200000
#define F_IN 128
#define HID 64
#define N_CLASSES 10
#define N_GRAPHS 256
#define EPSF 1e-5f

// ---------------- CSR build ----------------

__global__ void k_hist(const int* __restrict__ dst, int* __restrict__ cnt) {
    int e = blockIdx.x * blockDim.x + threadIdx.x;
    if (e < N_EDGES) atomicAdd(&cnt[dst[e]], 1);
}

__global__ void k_dinv(const int* __restrict__ cnt, float* __restrict__ dinv) {
    int i = blockIdx.x * blockDim.x + threadIdx.x;
    if (i < N_NODES) dinv[i] = rsqrtf((float)cnt[i] + 1.0f);
}

// single-block exclusive scan over N_NODES ints; writes offs[N] = total, cursor = offs[0..N)
__global__ __launch_bounds__(1024) void k_scan(const int* __restrict__ cnt,
                                               int* __restrict__ offs,
                                               int* __restrict__ cursor) {
    __shared__ int wsum[16];
    __shared__ int s_carry;
    int tid = threadIdx.x;
    int lane = tid & 63, wid = tid >> 6;
    if (tid == 0) s_carry = 0;
    __syncthreads();
    for (int base = 0; base < N_NODES; base += 1024) {
        int i = base + tid;
        int v = (i < N_NODES) ? cnt[i] : 0;
        int x = v;
        #pragma unroll
        for (int d = 1; d < 64; d <<= 1) {
            int y = __shfl_up(x, (unsigned)d);
            if (lane >= d) x += y;
        }
        if (lane == 63) wsum[wid] = x;
        __syncthreads();
        if (tid == 0) {
            int run = 0;
            for (int w = 0; w < 16; ++w) { int t = wsum[w]; wsum[w] = run; run += t; }
        }
        __syncthreads();
        int carry = s_carry;
        int excl = carry + wsum[wid] + (x - v);
        if (i < N_NODES) { offs[i] = excl; cursor[i] = excl; }
        __syncthreads();
        if (tid == 1023) s_carry = carry + wsum[15] + x;  // waves 0-14 excl + wave15 incl
        __syncthreads();
    }
    if (tid == 0) offs[N_NODES] = s_carry;
}

__global__ void k_fill(const int* __restrict__ esrc, const int* __restrict__ edst,
                       int* __restrict__ cursor, int* __restrict__ csr_src) {
    int e = blockIdx.x * blockDim.x + threadIdx.x;
    if (e < N_EDGES) {
        int d = edst[e];
        int pos = atomicAdd(&cursor[d], 1);
        csr_src[pos] = esrc[e];
    }
}

// ---------------- dense layers ----------------

// out[N,64] = A[N,K] @ W[K,64]; wave per row, lane = output feature
template <int K>
__global__ __launch_bounds__(256) void k_gemm(const float* __restrict__ A,
                                              const float* __restrict__ W,
                                              float* __restrict__ out) {
    __shared__ float sW[K * 64];
    for (int i = threadIdx.x; i < K * 64; i += 256) sW[i] = W[i];
    __syncthreads();
    int lane = threadIdx.x & 63;
    int wave = blockIdx.x * 4 + (threadIdx.x >> 6);
    int nw = gridDim.x * 4;
    for (int v = wave; v < N_NODES; v += nw) {
        const float* a = A + (size_t)v * K;
        float a0 = a[lane];
        float a1 = (K == 128) ? a[64 + lane] : 0.f;
        float acc = 0.f;
        #pragma unroll
        for (int k = 0; k < 64; ++k) acc += __shfl(a0, k) * sW[k * 64 + lane];
        if (K == 128) {
            #pragma unroll
            for (int k = 0; k < 64; ++k) acc += __shfl(a1, k) * sW[(64 + k) * 64 + lane];
        }
        out[(size_t)v * 64 + lane] = acc;
    }
}

// hpre[v] = sum_{u in in(v)} dinv[u]*dinv[v]*hw[u] + dinv[v]^2*hw[v] + b ; accumulate BN stats
__global__ __launch_bounds__(256) void k_agg(const float* __restrict__ hw,
                                             const int* __restrict__ offs,
                                             const int* __restrict__ csr_src,
                                             const float* __restrict__ dinv,
                                             const float* __restrict__ bias,
                                             float* __restrict__ hpre,
                                             float* __restrict__ stats) {
    int lane = threadIdx.x & 63;
    int wave = blockIdx.x * 4 + (threadIdx.x >> 6);
    int nw = gridDim.x * 4;
    float b = bias[lane];
    float lsum = 0.f, lsq = 0.f;
    for (int v = wave; v < N_NODES; v += nw) {
        float dv = dinv[v];
        int s = offs[v], e = offs[v + 1];
        float acc = dv * dv * hw[(size_t)v * 64 + lane];
        for (int j = s; j < e; ++j) {
            int u = csr_src[j];
            acc += (dinv[u] * dv) * hw[(size_t)u * 64 + lane];
        }
        acc += b;
        hpre[(size_t)v * 64 + lane] = acc;
        lsum += acc;
        lsq += acc * acc;
    }
    atomicAdd(&stats[lane], lsum);
    atomicAdd(&stats[64 + lane], lsq);
}

// h = relu(gamma*(hpre-mu)*rsqrt(var+eps)+beta), in-place ok; optionally fuse pooling
__global__ __launch_bounds__(256) void k_norm(const float* __restrict__ hpre,
                                              const float* __restrict__ stats,
                                              const float* __restrict__ gamma,
                                              const float* __restrict__ beta,
                                              float* __restrict__ hout,
                                              const int* __restrict__ batch,
                                              float* __restrict__ pmax,
                                              float* __restrict__ psum,
                                              float* __restrict__ gcnt,
                                              int do_pool) {
    int lane = threadIdx.x & 63;
    int wave = blockIdx.x * 4 + (threadIdx.x >> 6);
    int nw = gridDim.x * 4;
    const float invN = 1.0f / (float)N_NODES;
    float mu = stats[lane] * invN;
    float var = stats[64 + lane] * invN - mu * mu;
    float sc = rsqrtf(var + EPSF) * gamma[lane];
    float sh = beta[lane] - mu * sc;
    for (int v = wave; v < N_NODES; v += nw) {
        float h = hpre[(size_t)v * 64 + lane] * sc + sh;
        h = fmaxf(h, 0.f);
        hout[(size_t)v * 64 + lane] = h;
        if (do_pool) {
            int g = batch[v];
            atomicMax((int*)&pmax[(size_t)g * 64 + lane], __float_as_int(h));  // h >= 0
            atomicAdd(&psum[(size_t)g * 64 + lane], h);
            if (lane == 0) atomicAdd(&gcnt[g], 1.0f);
        }
    }
}

// ---------------- head MLP ----------------

__global__ __launch_bounds__(64) void k_mlp(const float* __restrict__ pmax,
                                            const float* __restrict__ psum,
                                            const float* __restrict__ gcnt,
                                            const float* __restrict__ lw1,
                                            const float* __restrict__ lb1,
                                            const float* __restrict__ lw2,
                                            const float* __restrict__ lb2,
                                            float* __restrict__ out) {
    __shared__ float emb[192];
    __shared__ float hid[64];
    int g = blockIdx.x;
    int j = threadIdx.x;
    float c = gcnt[g];
    float inv = 1.0f / fmaxf(c, 1.0f);
    float ps = psum[(size_t)g * 64 + j];
    emb[j] = pmax[(size_t)g * 64 + j];
    emb[64 + j] = ps * inv;
    emb[128 + j] = ps;
    __syncthreads();
    float acc = lb1[j];
    #pragma unroll 4
    for (int k = 0; k < 192; ++k) acc += emb[k] * lw1[k * 64 + j];
    hid[j] = fmaxf(acc, 0.f);
    __syncthreads();
    if (j < N_CLASSES) {
        float o = lb2[j];
        #pragma unroll 8
        for (int k = 0; k < 64; ++k) o += hid[k] * lw2[k * 10 + j];
        out[(size_t)g * 10 + j] = o;
    }
}

// ---------------- launch ----------------

extern "C" void kernel_launch(void* const* d_in, const int* in_sizes, int n_in,
                              void* d_out, int out_size, void* d_ws, size_t ws_size,
                              hipStream_t stream) {
    const float* x     = (const float*)d_in[0];
    const int* eidx    = (const int*)d_in[1];
    const int* batch   = (const int*)d_in[2];
    const float* W1    = (const float*)d_in[3];
    const float* b1    = (const float*)d_in[4];
    const float* W2    = (const float*)d_in[5];
    const float* b2    = (const float*)d_in[6];
    const float* gamma = (const float*)d_in[7];
    const float* beta  = (const float*)d_in[8];
    const float* lw1   = (const float*)d_in[9];
    const float* lb1   = (const float*)d_in[10];
    const float* lw2   = (const float*)d_in[11];
    const float* lb2   = (const float*)d_in[12];
    float* out = (float*)d_out;

    const int* e_src = eidx;
    const int* e_dst = eidx + N_EDGES;

    char* p = (char*)d_ws;
    auto carve = [&](size_t bytes) { char* r = p; p += (bytes + 255) & ~(size_t)255; return r; };
    // zero-initialized region (one memset covers all of these)
    int*   cnt   = (int*)carve((size_t)N_NODES * 4);
    float* stats = (float*)carve(3 * 128 * 4);
    float* pmax  = (float*)carve((size_t)N_GRAPHS * 64 * 4);
    float* psum  = (float*)carve((size_t)N_GRAPHS * 64 * 4);
    float* gcnt  = (float*)carve((size_t)N_GRAPHS * 4);
    size_t zero_bytes = (size_t)(p - (char*)d_ws);
    // scratch (no init needed)
    int*   offs    = (int*)carve((size_t)(N_NODES + 1) * 4);
    int*   cursor  = (int*)carve((size_t)N_NODES * 4);
    float* dinv    = (float*)carve((size_t)N_NODES * 4);
    int*   csr_src = (int*)carve((size_t)N_EDGES * 4);
    float* B0      = (float*)carve((size_t)N_NODES * 64 * 4);  // h @ W
    float* B1      = (float*)carve((size_t)N_NODES * 64 * 4);  // h_pre / h_act (in-place norm)

    hipMemsetAsync(d_ws, 0, zero_bytes, stream);

    // CSR by destination (reused for all 3 layers)
    k_hist<<<(N_EDGES + 255) / 256, 256, 0, stream>>>(e_dst, cnt);
    k_dinv<<<(N_NODES + 255) / 256, 256, 0, stream>>>(cnt, dinv);
    k_scan<<<1, 1024, 0, stream>>>(cnt, offs, cursor);
    k_fill<<<(N_EDGES + 255) / 256, 256, 0, stream>>>(e_src, e_dst, cursor, csr_src);

    // layer 1
    k_gemm<128><<<1024, 256, 0, stream>>>(x, W1, B0);
    k_agg<<<1024, 256, 0, stream>>>(B0, offs, csr_src, dinv, b1, B1, stats);
    k_norm<<<512, 256, 0, stream>>>(B1, stats, gamma, beta, B1, batch, pmax, psum, gcnt, 0);
    // layer 2
    k_gemm<64><<<1024, 256, 0, stream>>>(B1, W2, B0);
    k_agg<<<1024, 256, 0, stream>>>(B0, offs, csr_src, dinv, b2, B1, stats + 128);
    k_norm<<<512, 256, 0, stream>>>(B1, stats + 128, gamma, beta, B1, batch, pmax, psum, gcnt, 0);
    // layer 3 (fuse pooling into norm)
    k_gemm<64><<<1024, 256, 0, stream>>>(B1, W2, B0);
    k_agg<<<1024, 256, 0, stream>>>(B0, offs, csr_src, dinv, b2, B1, stats + 256);
    k_norm<<<512, 256, 0, stream>>>(B1, stats + 256, gamma, beta, B1, batch, pmax, psum, gcnt, 1);

    // head
    k_mlp<<<N_GRAPHS, 64, 0, stream>>>(pmax, psum, gcnt, lw1, lb1, lw2, lb2, out);
}

// Round 3
// 888.276 us; speedup vs baseline: 1.5229x; 1.5229x over previous
//
#include <hip/hip_runtime.h>

#define N_NODES 50000
#define N_EDGES 1200000
#define F_IN 128
#define HID 64
#define N_CLASSES 10
#define N_GRAPHS 256
#define EPSF 1e-5f

// ---------------- CSR build ----------------

__global__ void k_hist(const int* __restrict__ dst, int* __restrict__ cnt) {
    int e = blockIdx.x * blockDim.x + threadIdx.x;
    if (e < N_EDGES) atomicAdd(&cnt[dst[e]], 1);
}

// single-block exclusive scan over N_NODES ints; also emits dinv = rsqrt(cnt+1)
__global__ __launch_bounds__(1024) void k_scan(const int* __restrict__ cnt,
                                               int* __restrict__ offs,
                                               int* __restrict__ cursor,
                                               float* __restrict__ dinv) {
    __shared__ int wsum[16];
    __shared__ int s_carry;
    int tid = threadIdx.x;
    int lane = tid & 63, wid = tid >> 6;
    if (tid == 0) s_carry = 0;
    __syncthreads();
    for (int base = 0; base < N_NODES; base += 1024) {
        int i = base + tid;
        int v = (i < N_NODES) ? cnt[i] : 0;
        if (i < N_NODES) dinv[i] = rsqrtf((float)v + 1.0f);
        int x = v;
        #pragma unroll
        for (int d = 1; d < 64; d <<= 1) {
            int y = __shfl_up(x, (unsigned)d);
            if (lane >= d) x += y;
        }
        if (lane == 63) wsum[wid] = x;
        __syncthreads();
        if (tid == 0) {
            int run = 0;
            for (int w = 0; w < 16; ++w) { int t = wsum[w]; wsum[w] = run; run += t; }
        }
        __syncthreads();
        int carry = s_carry;
        int excl = carry + wsum[wid] + (x - v);
        if (i < N_NODES) { offs[i] = excl; cursor[i] = excl; }
        __syncthreads();
        if (tid == 1023) s_carry = carry + wsum[15] + x;  // waves 0-14 excl + wave15 incl
        __syncthreads();
    }
    if (tid == 0) offs[N_NODES] = s_carry;
}

// csr[pos] = {src, bits(dinv[src])} — one 8B load in the gather loop gets index+weight
__global__ void k_fill(const int* __restrict__ esrc, const int* __restrict__ edst,
                       const float* __restrict__ dinv,
                       int* __restrict__ cursor, int2* __restrict__ csr) {
    int e = blockIdx.x * blockDim.x + threadIdx.x;
    if (e < N_EDGES) {
        int d = edst[e];
        int s = esrc[e];
        int pos = atomicAdd(&cursor[d], 1);
        csr[pos] = make_int2(s, __float_as_int(dinv[s]));
    }
}

// ---------------- dense layers ----------------

// out[N,64] = A'[N,K] @ W[K,64]; wave per row, lane = output feature.
// NORM: A' = relu(A*sc + sh) with per-feature affine from prev layer's BN stats
// (fusing the k_norm pass of layers 1/2 into the next layer's GEMM A-load).
template <int K, bool NORM>
__global__ __launch_bounds__(256) void k_gemm(const float* __restrict__ A,
                                              const float* __restrict__ W,
                                              float* __restrict__ out,
                                              const float* __restrict__ stats,
                                              const float* __restrict__ gamma,
                                              const float* __restrict__ beta) {
    __shared__ float sW[K * 64];
    for (int i = threadIdx.x; i < K * 64; i += 256) sW[i] = W[i];
    __syncthreads();
    int lane = threadIdx.x & 63;
    int wave = blockIdx.x * 4 + (threadIdx.x >> 6);
    int nw = gridDim.x * 4;
    float sc = 1.f, sh = 0.f;
    if (NORM) {
        const float invN = 1.0f / (float)N_NODES;
        float mu = stats[lane] * invN;
        float var = stats[64 + lane] * invN - mu * mu;
        sc = rsqrtf(var + EPSF) * gamma[lane];
        sh = beta[lane] - mu * sc;
    }
    for (int v = wave; v < N_NODES; v += nw) {
        const float* a = A + (size_t)v * K;
        float a0 = a[lane];
        if (NORM) a0 = fmaxf(a0 * sc + sh, 0.f);
        float a1 = 0.f;
        if (K == 128) a1 = a[64 + lane];
        float acc = 0.f;
        #pragma unroll
        for (int k = 0; k < 64; ++k) acc += __shfl(a0, k) * sW[k * 64 + lane];
        if (K == 128) {
            #pragma unroll
            for (int k = 0; k < 64; ++k) acc += __shfl(a1, k) * sW[(64 + k) * 64 + lane];
        }
        out[(size_t)v * 64 + lane] = acc;
    }
}

// hpre[v] = dv * (dv*hw[v] + sum_u w_u*hw[u]) + b ; accumulate BN stats (LDS-staged)
__global__ __launch_bounds__(256) void k_agg(const float* __restrict__ hw,
                                             const int* __restrict__ offs,
                                             const int2* __restrict__ csr,
                                             const float* __restrict__ dinv,
                                             const float* __restrict__ bias,
                                             float* __restrict__ hpre,
                                             float* __restrict__ stats) {
    __shared__ float sred[128];
    if (threadIdx.x < 128) sred[threadIdx.x] = 0.f;
    __syncthreads();
    int lane = threadIdx.x & 63;
    int wave = blockIdx.x * 4 + (threadIdx.x >> 6);
    int nw = gridDim.x * 4;
    float b = bias[lane];
    float lsum = 0.f, lsq = 0.f;
    for (int v = wave; v < N_NODES; v += nw) {
        float dv = dinv[v];
        int s = offs[v], e = offs[v + 1];
        float inner = dv * hw[(size_t)v * 64 + lane];
        int j = s;
        // 4 independent row-gathers in flight per iteration (MLP)
        for (; j + 4 <= e; j += 4) {
            int2 p0 = csr[j], p1 = csr[j + 1], p2 = csr[j + 2], p3 = csr[j + 3];
            float h0 = hw[(size_t)p0.x * 64 + lane];
            float h1 = hw[(size_t)p1.x * 64 + lane];
            float h2 = hw[(size_t)p2.x * 64 + lane];
            float h3 = hw[(size_t)p3.x * 64 + lane];
            inner += __int_as_float(p0.y) * h0;
            inner += __int_as_float(p1.y) * h1;
            inner += __int_as_float(p2.y) * h2;
            inner += __int_as_float(p3.y) * h3;
        }
        for (; j < e; ++j) {
            int2 p = csr[j];
            inner += __int_as_float(p.y) * hw[(size_t)p.x * 64 + lane];
        }
        float acc = dv * inner + b;
        hpre[(size_t)v * 64 + lane] = acc;
        lsum += acc;
        lsq += acc * acc;
    }
    atomicAdd(&sred[lane], lsum);
    atomicAdd(&sred[64 + lane], lsq);
    __syncthreads();
    if (threadIdx.x < 128) atomicAdd(&stats[threadIdx.x], sred[threadIdx.x]);
}

// layer-3 only: h = relu(bn(hpre)) + fused 3-way pooling
__global__ __launch_bounds__(256) void k_norm_pool(const float* __restrict__ hpre,
                                                   const float* __restrict__ stats,
                                                   const float* __restrict__ gamma,
                                                   const float* __restrict__ beta,
                                                   const int* __restrict__ batch,
                                                   float* __restrict__ pmax,
                                                   float* __restrict__ psum,
                                                   float* __restrict__ gcnt) {
    int lane = threadIdx.x & 63;
    int wave = blockIdx.x * 4 + (threadIdx.x >> 6);
    int nw = gridDim.x * 4;
    const float invN = 1.0f / (float)N_NODES;
    float mu = stats[lane] * invN;
    float var = stats[64 + lane] * invN - mu * mu;
    float sc = rsqrtf(var + EPSF) * gamma[lane];
    float sh = beta[lane] - mu * sc;
    for (int v = wave; v < N_NODES; v += nw) {
        float h = hpre[(size_t)v * 64 + lane] * sc + sh;
        h = fmaxf(h, 0.f);
        int g = batch[v];
        atomicMax((int*)&pmax[(size_t)g * 64 + lane], __float_as_int(h));  // h >= 0, init 0
        atomicAdd(&psum[(size_t)g * 64 + lane], h);
        if (lane == 0) atomicAdd(&gcnt[g], 1.0f);
    }
}

// ---------------- head MLP ----------------

__global__ __launch_bounds__(64) void k_mlp(const float* __restrict__ pmax,
                                            const float* __restrict__ psum,
                                            const float* __restrict__ gcnt,
                                            const float* __restrict__ lw1,
                                            const float* __restrict__ lb1,
                                            const float* __restrict__ lw2,
                                            const float* __restrict__ lb2,
                                            float* __restrict__ out) {
    __shared__ float emb[192];
    __shared__ float hid[64];
    int g = blockIdx.x;
    int j = threadIdx.x;
    float c = gcnt[g];
    float inv = 1.0f / fmaxf(c, 1.0f);
    float ps = psum[(size_t)g * 64 + j];
    emb[j] = pmax[(size_t)g * 64 + j];
    emb[64 + j] = ps * inv;
    emb[128 + j] = ps;
    __syncthreads();
    float acc = lb1[j];
    #pragma unroll 4
    for (int k = 0; k < 192; ++k) acc += emb[k] * lw1[k * 64 + j];
    hid[j] = fmaxf(acc, 0.f);
    __syncthreads();
    if (j < N_CLASSES) {
        float o = lb2[j];
        #pragma unroll 8
        for (int k = 0; k < 64; ++k) o += hid[k] * lw2[k * 10 + j];
        out[(size_t)g * 10 + j] = o;
    }
}

// ---------------- launch ----------------

extern "C" void kernel_launch(void* const* d_in, const int* in_sizes, int n_in,
                              void* d_out, int out_size, void* d_ws, size_t ws_size,
                              hipStream_t stream) {
    const float* x     = (const float*)d_in[0];
    const int* eidx    = (const int*)d_in[1];
    const int* batch   = (const int*)d_in[2];
    const float* W1    = (const float*)d_in[3];
    const float* b1    = (const float*)d_in[4];
    const float* W2    = (const float*)d_in[5];
    const float* b2    = (const float*)d_in[6];
    const float* gamma = (const float*)d_in[7];
    const float* beta  = (const float*)d_in[8];
    const float* lw1   = (const float*)d_in[9];
    const float* lb1   = (const float*)d_in[10];
    const float* lw2   = (const float*)d_in[11];
    const float* lb2   = (const float*)d_in[12];
    float* out = (float*)d_out;

    const int* e_src = eidx;
    const int* e_dst = eidx + N_EDGES;

    char* p = (char*)d_ws;
    auto carve = [&](size_t bytes) { char* r = p; p += (bytes + 255) & ~(size_t)255; return r; };
    // zero-initialized region (one memset covers all of these)
    int*   cnt   = (int*)carve((size_t)N_NODES * 4);
    float* stats = (float*)carve(3 * 128 * 4);
    float* pmax  = (float*)carve((size_t)N_GRAPHS * 64 * 4);
    float* psum  = (float*)carve((size_t)N_GRAPHS * 64 * 4);
    float* gcnt  = (float*)carve((size_t)N_GRAPHS * 4);
    size_t zero_bytes = (size_t)(p - (char*)d_ws);
    // scratch (no init needed)
    int*   offs   = (int*)carve((size_t)(N_NODES + 1) * 4);
    int*   cursor = (int*)carve((size_t)N_NODES * 4);
    float* dinv   = (float*)carve((size_t)N_NODES * 4);
    int2*  csr    = (int2*)carve((size_t)N_EDGES * 8);
    float* B0     = (float*)carve((size_t)N_NODES * 64 * 4);  // h @ W
    float* B1     = (float*)carve((size_t)N_NODES * 64 * 4);  // h_pre

    hipMemsetAsync(d_ws, 0, zero_bytes, stream);

    // CSR by destination (reused for all 3 layers)
    k_hist<<<(N_EDGES + 255) / 256, 256, 0, stream>>>(e_dst, cnt);
    k_scan<<<1, 1024, 0, stream>>>(cnt, offs, cursor, dinv);
    k_fill<<<(N_EDGES + 255) / 256, 256, 0, stream>>>(e_src, e_dst, dinv, cursor, csr);

    // layer 1
    k_gemm<128, false><<<1024, 256, 0, stream>>>(x, W1, B0, nullptr, nullptr, nullptr);
    k_agg<<<2048, 256, 0, stream>>>(B0, offs, csr, dinv, b1, B1, stats);
    // layer 2 (norm+relu of layer 1 fused into A-load)
    k_gemm<64, true><<<1024, 256, 0, stream>>>(B1, W2, B0, stats, gamma, beta);
    k_agg<<<2048, 256, 0, stream>>>(B0, offs, csr, dinv, b2, B1, stats + 128);
    // layer 3 (norm+relu of layer 2 fused into A-load)
    k_gemm<64, true><<<1024, 256, 0, stream>>>(B1, W2, B0, stats + 128, gamma, beta);
    k_agg<<<2048, 256, 0, stream>>>(B0, offs, csr, dinv, b2, B1, stats + 256);
    // norm+relu of layer 3 + pooling
    k_norm_pool<<<1024, 256, 0, stream>>>(B1, stats + 256, gamma, beta, batch, pmax, psum, gcnt);

    // head
    k_mlp<<<N_GRAPHS, 64, 0, stream>>>(pmax, psum, gcnt, lw1, lb1, lw2, lb2, out);
}

// Round 5
// 725.097 us; speedup vs baseline: 1.8656x; 1.2250x over previous
//
#include <hip/hip_runtime.h>

#define N_NODES 50000
#define N_EDGES 1200000
#define F_IN 128
#define HID 64
#define N_CLASSES 10
#define N_GRAPHS 256
#define EPSF 1e-5f

// ---------------- CSR build ----------------

__global__ void k_hist(const int* __restrict__ dst, int* __restrict__ cnt) {
    int e = blockIdx.x * blockDim.x + threadIdx.x;
    if (e < N_EDGES) atomicAdd(&cnt[dst[e]], 1);
}

// single-block exclusive scan over N_NODES ints; also emits dinv = rsqrt(cnt+1)
__global__ __launch_bounds__(1024) void k_scan(const int* __restrict__ cnt,
                                               int* __restrict__ offs,
                                               int* __restrict__ cursor,
                                               float* __restrict__ dinv) {
    __shared__ int wsum[16];
    __shared__ int s_carry;
    int tid = threadIdx.x;
    int lane = tid & 63, wid = tid >> 6;
    if (tid == 0) s_carry = 0;
    __syncthreads();
    for (int base = 0; base < N_NODES; base += 1024) {
        int i = base + tid;
        int v = (i < N_NODES) ? cnt[i] : 0;
        if (i < N_NODES) dinv[i] = rsqrtf((float)v + 1.0f);
        int x = v;
        #pragma unroll
        for (int d = 1; d < 64; d <<= 1) {
            int y = __shfl_up(x, (unsigned)d);
            if (lane >= d) x += y;
        }
        if (lane == 63) wsum[wid] = x;
        __syncthreads();
        if (tid == 0) {
            int run = 0;
            for (int w = 0; w < 16; ++w) { int t = wsum[w]; wsum[w] = run; run += t; }
        }
        __syncthreads();
        int carry = s_carry;
        int excl = carry + wsum[wid] + (x - v);
        if (i < N_NODES) { offs[i] = excl; cursor[i] = excl; }
        __syncthreads();
        if (tid == 1023) s_carry = carry + wsum[15] + x;  // waves 0-14 excl + wave15 incl
        __syncthreads();
    }
    if (tid == 0) offs[N_NODES] = s_carry;
}

// csr[pos] = {src, bits(dinv[src])} — one 8B load in the gather loop gets index+weight
__global__ void k_fill(const int* __restrict__ esrc, const int* __restrict__ edst,
                       const float* __restrict__ dinv,
                       int* __restrict__ cursor, int2* __restrict__ csr) {
    int e = blockIdx.x * blockDim.x + threadIdx.x;
    if (e < N_EDGES) {
        int d = edst[e];
        int s = esrc[e];
        int pos = atomicAdd(&cursor[d], 1);
        csr[pos] = make_int2(s, __float_as_int(dinv[s]));
    }
}

// batch is sorted: gstart[g] = first node with batch >= g; gstart[N_GRAPHS] = N_NODES
__global__ void k_bounds(const int* __restrict__ batch, int* __restrict__ gstart) {
    int v = blockIdx.x * blockDim.x + threadIdx.x;
    if (v >= N_NODES) return;
    if (v == 0) {
        int b = batch[0];
        for (int g = 0; g <= b; ++g) gstart[g] = 0;
    } else {
        int b0 = batch[v - 1], b1 = batch[v];
        for (int g = b0 + 1; g <= b1; ++g) gstart[g] = v;
    }
    if (v == N_NODES - 1) {
        int b = batch[v];
        for (int g = b + 1; g <= N_GRAPHS; ++g) gstart[g] = N_NODES;
    }
}

// ---------------- dense layers ----------------

// out[N,64] = A'[N,K] @ W[K,64]; wave per row, lane = output feature.
// NORM: A' = relu(A*sc + sh) — prev layer's BN+ReLU fused into the A-load.
template <int K, bool NORM>
__global__ __launch_bounds__(256) void k_gemm(const float* __restrict__ A,
                                              const float* __restrict__ W,
                                              float* __restrict__ out,
                                              const float* __restrict__ stats,
                                              const float* __restrict__ gamma,
                                              const float* __restrict__ beta) {
    __shared__ float sW[K * 64];
    for (int i = threadIdx.x; i < K * 64; i += 256) sW[i] = W[i];
    __syncthreads();
    int lane = threadIdx.x & 63;
    int wave = blockIdx.x * 4 + (threadIdx.x >> 6);
    int nw = gridDim.x * 4;
    float sc = 1.f, sh = 0.f;
    if (NORM) {
        const float invN = 1.0f / (float)N_NODES;
        float mu = stats[lane] * invN;
        float var = stats[64 + lane] * invN - mu * mu;
        sc = rsqrtf(var + EPSF) * gamma[lane];
        sh = beta[lane] - mu * sc;
    }
    for (int v = wave; v < N_NODES; v += nw) {
        const float* a = A + (size_t)v * K;
        float a0 = a[lane];
        if (NORM) a0 = fmaxf(a0 * sc + sh, 0.f);
        float a1 = 0.f;
        if (K == 128) a1 = a[64 + lane];
        float acc = 0.f;
        #pragma unroll
        for (int k = 0; k < 64; ++k) acc += __shfl(a0, k) * sW[k * 64 + lane];
        if (K == 128) {
            #pragma unroll
            for (int k = 0; k < 64; ++k) acc += __shfl(a1, k) * sW[(64 + k) * 64 + lane];
        }
        out[(size_t)v * 64 + lane] = acc;
    }
}

// hpre[v] = dv * (dv*hw[v] + sum_u w_u*hw[u]) + b ; accumulate BN stats (LDS-staged)
__global__ __launch_bounds__(256) void k_agg(const float* __restrict__ hw,
                                             const int* __restrict__ offs,
                                             const int2* __restrict__ csr,
                                             const float* __restrict__ dinv,
                                             const float* __restrict__ bias,
                                             float* __restrict__ hpre,
                                             float* __restrict__ stats) {
    __shared__ float sred[128];
    if (threadIdx.x < 128) sred[threadIdx.x] = 0.f;
    __syncthreads();
    int lane = threadIdx.x & 63;
    int wave = blockIdx.x * 4 + (threadIdx.x >> 6);
    int nw = gridDim.x * 4;
    float b = bias[lane];
    float lsum = 0.f, lsq = 0.f;
    for (int v = wave; v < N_NODES; v += nw) {
        float dv = dinv[v];
        int s = offs[v], e = offs[v + 1];
        float inner = dv * hw[(size_t)v * 64 + lane];
        int j = s;
        // 4 independent row-gathers in flight per iteration (MLP)
        for (; j + 4 <= e; j += 4) {
            int2 p0 = csr[j], p1 = csr[j + 1], p2 = csr[j + 2], p3 = csr[j + 3];
            float h0 = hw[(size_t)p0.x * 64 + lane];
            float h1 = hw[(size_t)p1.x * 64 + lane];
            float h2 = hw[(size_t)p2.x * 64 + lane];
            float h3 = hw[(size_t)p3.x * 64 + lane];
            inner += __int_as_float(p0.y) * h0;
            inner += __int_as_float(p1.y) * h1;
            inner += __int_as_float(p2.y) * h2;
            inner += __int_as_float(p3.y) * h3;
        }
        for (; j < e; ++j) {
            int2 p = csr[j];
            inner += __int_as_float(p.y) * hw[(size_t)p.x * 64 + lane];
        }
        float acc = dv * inner + b;
        hpre[(size_t)v * 64 + lane] = acc;
        lsum += acc;
        lsq += acc * acc;
    }
    atomicAdd(&sred[lane], lsum);
    atomicAdd(&sred[64 + lane], lsq);
    __syncthreads();
    if (threadIdx.x < 128) atomicAdd(&stats[threadIdx.x], sred[threadIdx.x]);
}

// one block per graph: norm+relu layer-3 rows, register max/sum over the graph's
// contiguous node range, LDS tree-reduce, then fused head MLP. Zero atomics.
__global__ __launch_bounds__(256) void k_pool(const float* __restrict__ hpre,
                                              const float* __restrict__ stats,
                                              const float* __restrict__ gamma,
                                              const float* __restrict__ beta,
                                              const int* __restrict__ gstart,
                                              const float* __restrict__ lw1,
                                              const float* __restrict__ lb1,
                                              const float* __restrict__ lw2,
                                              const float* __restrict__ lb2,
                                              float* __restrict__ out) {
    __shared__ float smax[4][64];
    __shared__ float ssum[4][64];
    __shared__ float emb[192];
    __shared__ float hid[64];
    int g = blockIdx.x;
    int lane = threadIdx.x & 63;
    int wid = threadIdx.x >> 6;
    int s = gstart[g], e = gstart[g + 1];

    const float invN = 1.0f / (float)N_NODES;
    float mu = stats[lane] * invN;
    float var = stats[64 + lane] * invN - mu * mu;
    float sc = rsqrtf(var + EPSF) * gamma[lane];
    float sh = beta[lane] - mu * sc;

    float mx = 0.f, sm = 0.f;  // post-relu values are >= 0; empty graph -> 0 (matches ref)
    for (int v = s + wid; v < e; v += 4) {
        float h = fmaxf(hpre[(size_t)v * 64 + lane] * sc + sh, 0.f);
        mx = fmaxf(mx, h);
        sm += h;
    }
    smax[wid][lane] = mx;
    ssum[wid][lane] = sm;
    __syncthreads();
    if (wid == 0) {
        float m = fmaxf(fmaxf(smax[0][lane], smax[1][lane]), fmaxf(smax[2][lane], smax[3][lane]));
        float su = ssum[0][lane] + ssum[1][lane] + ssum[2][lane] + ssum[3][lane];
        float inv = 1.0f / fmaxf((float)(e - s), 1.0f);
        emb[lane] = m;
        emb[64 + lane] = su * inv;
        emb[128 + lane] = su;
    }
    __syncthreads();
    if (wid == 0) {
        float acc = lb1[lane];
        #pragma unroll 4
        for (int k = 0; k < 192; ++k) acc += emb[k] * lw1[k * 64 + lane];
        hid[lane] = fmaxf(acc, 0.f);
    }
    __syncthreads();
    if (threadIdx.x < N_CLASSES) {
        int j = threadIdx.x;
        float o = lb2[j];
        #pragma unroll 8
        for (int k = 0; k < 64; ++k) o += hid[k] * lw2[k * 10 + j];
        out[(size_t)g * 10 + j] = o;
    }
}

// ---------------- launch ----------------

extern "C" void kernel_launch(void* const* d_in, const int* in_sizes, int n_in,
                              void* d_out, int out_size, void* d_ws, size_t ws_size,
                              hipStream_t stream) {
    const float* x     = (const float*)d_in[0];
    const int* eidx    = (const int*)d_in[1];
    const int* batch   = (const int*)d_in[2];
    const float* W1    = (const float*)d_in[3];
    const float* b1    = (const float*)d_in[4];
    const float* W2    = (const float*)d_in[5];
    const float* b2    = (const float*)d_in[6];
    const float* gamma = (const float*)d_in[7];
    const float* beta  = (const float*)d_in[8];
    const float* lw1   = (const float*)d_in[9];
    const float* lb1   = (const float*)d_in[10];
    const float* lw2   = (const float*)d_in[11];
    const float* lb2   = (const float*)d_in[12];
    float* out = (float*)d_out;

    const int* e_src = eidx;
    const int* e_dst = eidx + N_EDGES;

    char* p = (char*)d_ws;
    auto carve = [&](size_t bytes) { char* r = p; p += (bytes + 255) & ~(size_t)255; return r; };
    // zero-initialized region (one memset covers these)
    int*   cnt   = (int*)carve((size_t)N_NODES * 4);
    float* stats = (float*)carve(3 * 128 * 4);
    size_t zero_bytes = (size_t)(p - (char*)d_ws);
    // scratch (no init needed)
    int*   offs   = (int*)carve((size_t)(N_NODES + 1) * 4);
    int*   cursor = (int*)carve((size_t)N_NODES * 4);
    float* dinv   = (float*)carve((size_t)N_NODES * 4);
    int*   gstart = (int*)carve((size_t)(N_GRAPHS + 1) * 4);
    int2*  csr    = (int2*)carve((size_t)N_EDGES * 8);
    float* B0     = (float*)carve((size_t)N_NODES * 64 * 4);  // h @ W
    float* B1     = (float*)carve((size_t)N_NODES * 64 * 4);  // h_pre

    hipMemsetAsync(d_ws, 0, zero_bytes, stream);

    // CSR by destination (reused for all 3 layers) + graph segment bounds
    k_hist<<<(N_EDGES + 255) / 256, 256, 0, stream>>>(e_dst, cnt);
    k_scan<<<1, 1024, 0, stream>>>(cnt, offs, cursor, dinv);
    k_fill<<<(N_EDGES + 255) / 256, 256, 0, stream>>>(e_src, e_dst, dinv, cursor, csr);
    k_bounds<<<(N_NODES + 255) / 256, 256, 0, stream>>>(batch, gstart);

    // layer 1
    k_gemm<128, false><<<1024, 256, 0, stream>>>(x, W1, B0, nullptr, nullptr, nullptr);
    k_agg<<<2048, 256, 0, stream>>>(B0, offs, csr, dinv, b1, B1, stats);
    // layer 2 (norm+relu of layer 1 fused into A-load)
    k_gemm<64, true><<<1024, 256, 0, stream>>>(B1, W2, B0, stats, gamma, beta);
    k_agg<<<2048, 256, 0, stream>>>(B0, offs, csr, dinv, b2, B1, stats + 128);
    // layer 3 (norm+relu of layer 2 fused into A-load)
    k_gemm<64, true><<<1024, 256, 0, stream>>>(B1, W2, B0, stats + 128, gamma, beta);
    k_agg<<<2048, 256, 0, stream>>>(B0, offs, csr, dinv, b2, B1, stats + 256);
    // norm+relu layer 3 + segmented pooling + head MLP (no atomics)
    k_pool<<<N_GRAPHS, 256, 0, stream>>>(B1, stats + 256, gamma, beta, gstart,
                                         lw1, lb1, lw2, lb2, out);
}